// Round 6
// baseline (79.956 us; speedup 1.0000x reference)
//
#include <hip/hip_runtime.h>

#define DIVN 8
#define NB 32
#define NBLK 6144                 // 96 images * 64 blocks
#define NCHUNK 1536               // img*16 + bi*2 + half

typedef float floatx4 __attribute__((ext_vector_type(4)));

__device__ __forceinline__ void gll16(const void* g, void* l) {
    __builtin_amdgcn_global_load_lds(
        (const __attribute__((address_space(1))) void*)g,
        (__attribute__((address_space(3))) void*)l, 16, 0, 0);
}

// Stage 1: per-wave DMA pipeline. Each WG owns a contiguous 256 KB chunk
// (64 rows); wave w owns byte-quarter w of every 4 KB row. Ring of 4 slots
// per wave in LDS; global_load_lds keeps 3-4 KB in flight per wave with
// zero VGPR cost; counted vmcnt(3) per iteration (never 0 in the loop).
// No __syncthreads: waves stage and consume only their own LDS region.
__global__ __launch_bounds__(256) void stats_kernel(
    const float* __restrict__ x,
    double* __restrict__ wsum,   // [2][NBLK]
    float* __restrict__ wmn,     // [2][NBLK]
    float* __restrict__ wmx) {   // [2][NBLK]
    __shared__ floatx4 lds[4][4][64];   // [slot][wave][lane] = 16 KB
    const int ch  = blockIdx.x;          // 0..1535
    const int tid = threadIdx.x;
    const int w   = tid >> 6;            // wave 0..3
    const int l   = tid & 63;

    // wave w, lane l always reads float4-column w*64+l -> bj = tid>>5 fixed.
    const char* g0 = (const char*)x + (size_t)ch * (64 * 4096) + w * 1024 + l * 16;

    double s = 0.0;
    float mn = 3.402823466e38f;
    float mx = -3.402823466e38f;

    // Prologue: rows 0..2 into slots 0..2.
    gll16(g0,            &lds[0][w][0]);
    gll16(g0 + 4096,     &lds[1][w][0]);
    gll16(g0 + 2 * 4096, &lds[2][w][0]);

#define CONSUME(i) do {                                              \
        const floatx4 v = lds[(i) & 3][w][l];                        \
        s += (double)((v.x + v.y) + (v.z + v.w));                    \
        mn = fminf(mn, fminf(fminf(v.x, v.y), fminf(v.z, v.w)));     \
        mx = fmaxf(mx, fmaxf(fmaxf(v.x, v.y), fmaxf(v.z, v.w)));     \
    } while (0)

    for (int i = 0; i < 61; ++i) {
        gll16(g0 + (size_t)(i + 3) * 4096, &lds[(i + 3) & 3][w][0]);
        asm volatile("s_waitcnt vmcnt(3)" ::: "memory");   // row i landed
        CONSUME(i);
    }
    asm volatile("s_waitcnt vmcnt(2)" ::: "memory");
    CONSUME(61);
    asm volatile("s_waitcnt vmcnt(1)" ::: "memory");
    CONSUME(62);
    asm volatile("s_waitcnt vmcnt(0)" ::: "memory");
    CONSUME(63);
#undef CONSUME

    // Reduce within 32-lane groups (one group per bj).
    for (int off = 16; off > 0; off >>= 1) {
        s  += __shfl_down(s, off, 32);
        mn  = fminf(mn, __shfl_down(mn, off, 32));
        mx  = fmaxf(mx, __shfl_down(mx, off, 32));
    }

    if ((tid & 31) == 0) {
        const int bj   = tid >> 5;
        const int half = ch & 1;
        const int bi   = (ch >> 1) & 7;
        const int img  = ch >> 4;
        const int g    = img * 64 + bi * 8 + bj;
        wsum[half * NBLK + g] = s;
        wmn [half * NBLK + g] = mn;
        wmx [half * NBLK + g] = mx;
    }
}

// Stage 2: combine halves, compute pair terms, reduce to scalar.
__global__ __launch_bounds__(256) void pair_reduce_kernel(
    const double* __restrict__ wsum,
    const float* __restrict__ wmn,
    const float* __restrict__ wmx,
    float* __restrict__ out) {
    const int tid = threadIdx.x;
    double acc = 0.0;

    for (int item = tid; item < NB * DIVN * DIVN; item += 256) {
        const int p = item & 63;        // bi*8 + bj
        const int b = item >> 6;
        float m[3], n[3], X[3];
        #pragma unroll
        for (int c = 0; c < 3; ++c) {
            const int i = (b * 3 + c) * 64 + p;
            m[c] = (float)((wsum[i] + wsum[NBLK + i]) * (1.0 / 16384.0));
            n[c] = fminf(wmn[i], wmn[NBLK + i]);
            X[c] = fmaxf(wmx[i], wmx[NBLK + i]);
        }
        if (!((n[0] > X[1]) || (X[0] < n[1]))) { const float d = m[0] - m[1]; acc += (double)(d * d); }
        if (!((n[1] > X[2]) || (X[1] < n[2]))) { const float d = m[1] - m[2]; acc += (double)(d * d); }
        if (!((n[0] > X[2]) || (X[0] < n[2]))) { const float d = m[0] - m[2]; acc += (double)(d * d); }
    }

    __shared__ double sacc[256];
    sacc[tid] = acc;
    __syncthreads();
    for (int off = 128; off > 0; off >>= 1) {
        if (tid < off) sacc[tid] += sacc[tid + off];
        __syncthreads();
    }
    if (tid == 0) out[0] = (float)(sacc[0] * (1.0 / (DIVN * DIVN)));
}

extern "C" void kernel_launch(void* const* d_in, const int* in_sizes, int n_in,
                              void* d_out, int out_size, void* d_ws, size_t ws_size,
                              hipStream_t stream) {
    const float* x = (const float*)d_in[0];
    float* out = (float*)d_out;

    // ws layout: doubles first (alignment), then floats.
    double* wsum = (double*)d_ws;                    // 2*NBLK doubles
    float*  wmn  = (float*)(wsum + 2 * NBLK);        // 2*NBLK floats
    float*  wmx  = wmn + 2 * NBLK;                   // 2*NBLK floats

    stats_kernel<<<NCHUNK, 256, 0, stream>>>(x, wsum, wmn, wmx);
    pair_reduce_kernel<<<1, 256, 0, stream>>>(wsum, wmn, wmx, out);
}

// Round 7
// 67.735 us; speedup vs baseline: 1.1804x; 1.1804x over previous
//
#include <hip/hip_runtime.h>

#define DIVN 8
#define NB 32
#define NBLK 6144                 // 96 images * 64 blocks
#define NBAND 768                 // img*8 + bi  (128-row bands)

typedef float floatx4 __attribute__((ext_vector_type(4)));

// Stage 1: each WG (512 threads) owns a contiguous 512 KB band (128 rows of
// one image = one full block-row). Thread tid reads float4-column (tid&255)
// in row-half (tid>>8); its bj = (tid&255)>>5 is FIXED -> scalar accumulators,
// shfl reduce within 32-lane groups, tiny LDS exchange to combine halves,
// final packed float4{mean,min,max,0} per block.
__global__ __launch_bounds__(512) void stats_kernel(
    const float* __restrict__ x,
    floatx4* __restrict__ stats) {    // [NBLK]
    const int ch  = blockIdx.x;            // 0..767
    const int tid = threadIdx.x;           // 0..511
    const int col = tid & 255;             // float4 column
    const int rh  = tid >> 8;              // row half 0/1
    const float* base = x + (size_t)ch * (128 * 1024) + (size_t)rh * (64 * 1024) + col * 4;

    double s = 0.0;
    float mn = 3.402823466e38f;
    float mx = -3.402823466e38f;

    #pragma unroll 8
    for (int i = 0; i < 64; ++i) {
        const floatx4 v = __builtin_nontemporal_load(
            reinterpret_cast<const floatx4*>(base + (size_t)i * 1024));
        s += (double)((v.x + v.y) + (v.z + v.w));
        mn = fminf(mn, fminf(fminf(v.x, v.y), fminf(v.z, v.w)));
        mx = fmaxf(mx, fmaxf(fmaxf(v.x, v.y), fmaxf(v.z, v.w)));
    }

    // Reduce within 32-lane groups (one group per (bj, half)).
    for (int off = 16; off > 0; off >>= 1) {
        s  += __shfl_down(s, off, 32);
        mn  = fminf(mn, __shfl_down(mn, off, 32));
        mx  = fmaxf(mx, __shfl_down(mx, off, 32));
    }

    __shared__ double lsum[16];
    __shared__ float  lmn[16], lmx[16];
    if ((tid & 31) == 0) {
        const int g = tid >> 5;            // 0..15 : (half<<3) | bj
        lsum[g] = s; lmn[g] = mn; lmx[g] = mx;
    }
    __syncthreads();

    if (tid < 8) {                          // tid = bj
        const double st = lsum[tid] + lsum[tid + 8];     // half0 + half1, fixed order
        floatx4 r;
        r.x = (float)(st * (1.0 / 16384.0));
        r.y = fminf(lmn[tid], lmn[tid + 8]);
        r.z = fmaxf(lmx[tid], lmx[tid + 8]);
        r.w = 0.0f;
        const int img = ch >> 3;
        const int bi  = ch & 7;
        stats[img * 64 + bi * 8 + tid] = r;
    }
}

// Stage 2: single WG; 98 KB of packed stats, 24 independent float4 loads
// per thread, pair terms, LDS tree reduce.
__global__ __launch_bounds__(256) void pair_reduce_kernel(
    const floatx4* __restrict__ stats,
    float* __restrict__ out) {
    const int tid = threadIdx.x;
    double acc = 0.0;

    for (int item = tid; item < NB * 64; item += 256) {
        const int p = item & 63;        // bi*8 + bj
        const int b = item >> 6;
        const floatx4 s0 = stats[(b * 3 + 0) * 64 + p];
        const floatx4 s1 = stats[(b * 3 + 1) * 64 + p];
        const floatx4 s2 = stats[(b * 3 + 2) * 64 + p];

        if (!((s0.y > s1.z) || (s0.z < s1.y))) { const float d = s0.x - s1.x; acc += (double)(d * d); }
        if (!((s1.y > s2.z) || (s1.z < s2.y))) { const float d = s1.x - s2.x; acc += (double)(d * d); }
        if (!((s0.y > s2.z) || (s0.z < s2.y))) { const float d = s0.x - s2.x; acc += (double)(d * d); }
    }

    __shared__ double sacc[256];
    sacc[tid] = acc;
    __syncthreads();
    for (int off = 128; off > 0; off >>= 1) {
        if (tid < off) sacc[tid] += sacc[tid + off];
        __syncthreads();
    }
    if (tid == 0) out[0] = (float)(sacc[0] * (1.0 / (DIVN * DIVN)));
}

extern "C" void kernel_launch(void* const* d_in, const int* in_sizes, int n_in,
                              void* d_out, int out_size, void* d_ws, size_t ws_size,
                              hipStream_t stream) {
    const float* x = (const float*)d_in[0];
    float* out = (float*)d_out;
    floatx4* stats = (floatx4*)d_ws;     // NBLK float4 = 98304 B

    stats_kernel<<<NBAND, 512, 0, stream>>>(x, stats);
    pair_reduce_kernel<<<1, 256, 0, stream>>>(stats, out);
}